// Round 1
// baseline (1723.643 us; speedup 1.0000x reference)
//
#include <hip/hip_runtime.h>
#include <hip/hip_bf16.h>
#include <cstdint>

#define NN    50000
#define NE    1600000
#define NG    512
#define F     64        // ATOM_FEA
#define ED    32        // EDGE_DIM
#define ZIN   160       // 2F + ED
#define NC    128       // fused Wf|Ws output cols
#define HF    128       // H_FEA
#define NCONV 3
#define BN_EPS 1e-5f
#define AS    168       // LDS row stride (bf16 elems) for 160-wide rows (16B-aligned, 2-way-conflict only)

typedef __bf16 bf16_t;
typedef bf16_t bf16x8 __attribute__((ext_vector_type(8)));
typedef float  f32x16 __attribute__((ext_vector_type(16)));

__device__ __forceinline__ bf16x8 lds_load8(const bf16_t* p, int idx) {
  // two ds_read_b64: elems 0..3 = k lo half (g*4..g*4+3), elems 4..7 = k hi half (+8)
  union { uint2 u[2]; bf16x8 v; } t;
  t.u[0] = *(const uint2*)(p + idx);
  t.u[1] = *(const uint2*)(p + idx + 8);
  return t.v;
}

__global__ void k_embed(const int* __restrict__ x, const float* __restrict__ emb,
                        float* __restrict__ h32, bf16_t* __restrict__ hb) {
  int i = blockIdx.x * 256 + threadIdx.x;
  if (i >= NN * F) return;
  int node = i >> 6, c = i & 63;
  float v = emb[x[node] * F + c];
  h32[i] = v;
  hb[i] = (bf16_t)v;
}

__global__ void k_wprep(const float* __restrict__ Wf, const float* __restrict__ Ws,
                        bf16_t* __restrict__ Wt) {
  int i = blockIdx.x * 256 + threadIdx.x;  // NCONV*ZIN*NC = 61440
  if (i >= NCONV * ZIN * NC) return;
  int l = i / (ZIN * NC), r = i % (ZIN * NC), k = r / NC, c = r % NC;
  float v = (c < F) ? Wf[(l * ZIN + k) * F + c] : Ws[(l * ZIN + k) * F + (c - F)];
  Wt[(l * NC + c) * ZIN + k] = (bf16_t)v;   // transposed: Wt[l][c][k]
}

__launch_bounds__(256, 1)
__global__ void k_edges(const int* __restrict__ ei, const float* __restrict__ ea,
                        const bf16_t* __restrict__ hb, const bf16_t* __restrict__ Wt,
                        const float* __restrict__ bfv, const float* __restrict__ bsv,
                        float* __restrict__ agg, int layer) {
  extern __shared__ char smem[];
  bf16_t* Ash  = (bf16_t*)smem;                            // [256][AS] z-tile
  bf16_t* Bsh  = (bf16_t*)(smem + 256 * AS * 2);           // [128][AS] W^T
  int*    dstL = (int*)(smem + 256 * AS * 2 + 128 * AS * 2);

  const int tid = threadIdx.x;
  const int e0  = blockIdx.x * 256;

  dstL[tid] = ei[NE + e0 + tid];  // edge_index row1 = dst

  // stage W^T for this layer
  const bf16_t* W = Wt + layer * NC * ZIN;
  for (int i = tid; i < (NC * ZIN) / 8; i += 256) {
    int c = i / (ZIN / 8), kk = (i % (ZIN / 8)) * 8;
    *(uint4*)(Bsh + c * AS + kk) = *(const uint4*)(W + c * ZIN + kk);
  }
  __syncthreads();

  // stage z = [h[dst] || h[src] || ea] as bf16
  for (int i = tid; i < 256 * 8; i += 256) {
    int e = i >> 3, q = (i & 7) * 8;
    *(uint4*)(Ash + e * AS + q) = *(const uint4*)(hb + dstL[e] * F + q);
  }
  for (int i = tid; i < 256 * 8; i += 256) {
    int e = i >> 3, q = (i & 7) * 8;
    *(uint4*)(Ash + e * AS + F + q) = *(const uint4*)(hb + ei[e0 + e] * F + q);
  }
  for (int i = tid; i < 256 * 4; i += 256) {
    int e = i >> 2, q = (i & 3) * 8;
    const float* pa = ea + (e0 + e) * ED + q;
    float4 x0 = *(const float4*)pa, x1 = *(const float4*)(pa + 4);
    union { bf16_t h[8]; uint4 u; } pk;
    pk.h[0] = (bf16_t)x0.x; pk.h[1] = (bf16_t)x0.y; pk.h[2] = (bf16_t)x0.z; pk.h[3] = (bf16_t)x0.w;
    pk.h[4] = (bf16_t)x1.x; pk.h[5] = (bf16_t)x1.y; pk.h[6] = (bf16_t)x1.z; pk.h[7] = (bf16_t)x1.w;
    *(uint4*)(Ash + e * AS + 2 * F + q) = pk.u;
  }
  __syncthreads();

  const int w  = tid >> 6;   // wave id: edges [w*64, w*64+64)
  const int l  = tid & 63;
  const int lr = l & 31;
  const int g  = l >> 5;

  f32x16 acc[2][4] = {};

  #pragma unroll 2
  for (int ks = 0; ks < 10; ++ks) {
    const int k0 = ks * 16;
    bf16x8 af[2], bf8[4];
    #pragma unroll
    for (int r = 0; r < 2; ++r)
      af[r] = lds_load8(Ash, (w * 64 + r * 32 + lr) * AS + k0 + g * 4);
    #pragma unroll
    for (int n = 0; n < 4; ++n)
      bf8[n] = lds_load8(Bsh, (n * 32 + lr) * AS + k0 + g * 4);
    #pragma unroll
    for (int r = 0; r < 2; ++r)
      #pragma unroll
      for (int n = 0; n < 4; ++n)
        acc[r][n] = __builtin_amdgcn_mfma_f32_32x32x16_bf16(af[r], bf8[n], acc[r][n], 0, 0, 0);
  }

  // epilogue: m = sigmoid(f + bf) * softplus(s + bs); scatter-add to agg[dst]
  const float* bfl = bfv + layer * F;
  const float* bsl = bsv + layer * F;
  #pragma unroll
  for (int r = 0; r < 2; ++r) {
    #pragma unroll
    for (int n = 0; n < 2; ++n) {          // f tiles 0,1 pair with s tiles 2,3
      const int c = n * 32 + lr;
      const float bfc = bfl[c], bsc = bsl[c];
      f32x16 vf = acc[r][n], vs = acc[r][n + 2];
      #pragma unroll
      for (int q = 0; q < 16; ++q) {
        int row = (q & 3) + 8 * (q >> 2) + 4 * g;   // verified 32x32 C/D row map
        int e = w * 64 + r * 32 + row;
        float fv = vf[q] + bfc;
        float sv = vs[q] + bsc;
        float sig = 1.0f / (1.0f + __expf(-fv));
        float sp  = (sv > 20.0f) ? sv : __logf(1.0f + __expf(sv));
        atomicAdd(agg + dstL[e] * F + c, sig * sp);
      }
    }
  }
}

__global__ void k_update(const float* __restrict__ agg, const float* __restrict__ gam,
                         const float* __restrict__ bet, const float* __restrict__ mu,
                         const float* __restrict__ var, float* __restrict__ h32,
                         bf16_t* __restrict__ hb, int layer) {
  int i = blockIdx.x * 256 + threadIdx.x;
  if (i >= NN * F) return;
  int c = i & 63;
  float sc = gam[layer * F + c] * rsqrtf(var[layer * F + c] + BN_EPS);
  float sh = bet[layer * F + c] - mu[layer * F + c] * sc;
  float v = agg[i] * sc + sh + h32[i];
  v = fmaxf(v, 0.0f);
  h32[i] = v;
  hb[i] = (bf16_t)v;
}

__device__ __forceinline__ int lowb(const int* a, int n, int v) {
  int lo = 0, hi = n;
  while (lo < hi) { int mid = (lo + hi) >> 1; if (a[mid] < v) lo = mid + 1; else hi = mid; }
  return lo;
}

__global__ void k_pool_mlp(const float* __restrict__ h32, const int* __restrict__ batch,
                           const float* __restrict__ W1, const float* __restrict__ b1,
                           const float* __restrict__ W2, const float* __restrict__ b2,
                           float* __restrict__ out) {
  __shared__ float pooled[F];
  __shared__ float ps[HF];
  __shared__ float red[HF];
  const int gph = blockIdx.x;
  const int t = threadIdx.x;   // 128 threads
  const int lo = lowb(batch, NN, gph);
  const int hi = lowb(batch, NN, gph + 1);

  float s = 0.f;
  for (int i = lo + (t >> 6); i < hi; i += 2) s += h32[(size_t)i * F + (t & 63)];
  ps[t] = s;
  __syncthreads();
  if (t < F) {
    float tot = ps[t] + ps[t + F];
    pooled[t] = tot / fmaxf((float)(hi - lo), 1.0f);
  }
  __syncthreads();

  float a = b1[t];
  for (int c = 0; c < F; ++c) a += pooled[c] * W1[c * HF + t];
  a = fmaxf(a, 0.f);
  red[t] = a * W2[t];
  __syncthreads();
  for (int sdv = 64; sdv > 0; sdv >>= 1) {
    if (t < sdv) red[t] += red[t + sdv];
    __syncthreads();
  }
  if (t == 0) out[gph] = red[0] + b2[0];
}

extern "C" void kernel_launch(void* const* d_in, const int* in_sizes, int n_in,
                              void* d_out, int out_size, void* d_ws, size_t ws_size,
                              hipStream_t stream) {
  const int*   x    = (const int*)d_in[0];
  const int*   ei   = (const int*)d_in[1];
  const float* ea   = (const float*)d_in[2];
  const int*   batch= (const int*)d_in[3];
  const float* emb  = (const float*)d_in[4];
  const float* Wf   = (const float*)d_in[5];
  const float* bfb  = (const float*)d_in[6];
  const float* Ws   = (const float*)d_in[7];
  const float* bsb  = (const float*)d_in[8];
  const float* gam  = (const float*)d_in[9];
  const float* bet  = (const float*)d_in[10];
  const float* mu   = (const float*)d_in[11];
  const float* var  = (const float*)d_in[12];
  const float* W1   = (const float*)d_in[13];
  const float* b1   = (const float*)d_in[14];
  const float* W2   = (const float*)d_in[15];
  const float* b2   = (const float*)d_in[16];
  float* out = (float*)d_out;

  char* p = (char*)d_ws;
  auto take = [&](size_t bytes) { char* q = p; p += (bytes + 255) & ~(size_t)255; return q; };
  float*  h32 = (float*)take((size_t)NN * F * 4);
  bf16_t* hb  = (bf16_t*)take((size_t)NN * F * 2);
  float*  agg = (float*)take((size_t)NN * F * 4);
  bf16_t* Wt  = (bf16_t*)take((size_t)NCONV * NC * ZIN * 2);

  k_embed<<<(NN * F + 255) / 256, 256, 0, stream>>>(x, emb, h32, hb);
  k_wprep<<<(NCONV * ZIN * NC + 255) / 256, 256, 0, stream>>>(Wf, Ws, Wt);

  const size_t smem = 256 * AS * 2 + 128 * AS * 2 + 256 * 4;  // ~130 KB
  hipFuncSetAttribute((const void*)k_edges, hipFuncAttributeMaxDynamicSharedMemorySize, (int)smem);

  for (int layer = 0; layer < NCONV; ++layer) {
    hipMemsetAsync(agg, 0, (size_t)NN * F * 4, stream);
    k_edges<<<NE / 256, 256, smem, stream>>>(ei, ea, hb, Wt, bfb, bsb, agg, layer);
    k_update<<<(NN * F + 255) / 256, 256, 0, stream>>>(agg, gam, bet, mu, var, h32, hb, layer);
  }

  k_pool_mlp<<<NG, HF, 0, stream>>>(h32, batch, W1, b1, W2, b2, out);
}